// Round 5
// baseline (297.952 us; speedup 1.0000x reference)
//
#include <hip/hip_runtime.h>

#define H_  192
#define W_  192
#define HW  36864
#define B_  4

typedef __attribute__((ext_vector_type(8))) short short8;
typedef __attribute__((ext_vector_type(4))) float f32x4;
typedef __attribute__((ext_vector_type(4))) unsigned int u32x4;
typedef unsigned short ushort_t;
typedef unsigned int uint_t;

__device__ __forceinline__ ushort_t f2bf(float v) {
    uint_t u = __builtin_bit_cast(uint_t, v);
    u += 0x7FFFu + ((u >> 16) & 1u);   // RNE
    return (ushort_t)(u >> 16);
}
__device__ __forceinline__ float bflo(uint_t u) {
    uint_t w = u << 16; return __builtin_bit_cast(float, w);
}
__device__ __forceinline__ float bfhi(uint_t u) {
    uint_t w = u & 0xFFFF0000u; return __builtin_bit_cast(float, w);
}
__device__ __forceinline__ short8 zero8() {
    u32x4 z = {0u, 0u, 0u, 0u};
    return __builtin_bit_cast(short8, z);
}

// ============ K0: weight prep ============
__global__ void prep_kernel(const float* __restrict__ dw, const float* __restrict__ db,
                            const float* __restrict__ g, const float* __restrict__ be,
                            const float* __restrict__ mu, const float* __restrict__ var,
                            const float* __restrict__ ow,
                            ushort_t* __restrict__ w_bf, ushort_t* __restrict__ w_off,
                            float* __restrict__ scale, float* __restrict__ shift) {
    int idx = blockIdx.x * 256 + threadIdx.x;
    if (idx < 36864) {
        int tap = idx >> 12, o = (idx >> 6) & 63, c = idx & 63;
        w_bf[idx] = f2bf(dw[(o * 64 + c) * 9 + tap]);
    }
    int idx2 = idx - 36864;
    if (idx2 >= 0 && idx2 < 18432) {
        int tap = idx2 >> 11, o = (idx2 >> 6) & 31, c = idx2 & 63;
        w_off[idx2] = (o < 18) ? f2bf(ow[(o * 64 + c) * 9 + tap]) : (ushort_t)0;
    }
    if (idx < 64) {
        float s = g[idx] * rsqrtf(var[idx] + 1e-5f);
        scale[idx] = s;
        shift[idx] = (db[idx] - mu[idx]) * s + be[idx];
    }
}

// ============ KT: x [B,C,HW] f32 -> x_t [B,HW,C] bf16 ============
__global__ __launch_bounds__(256) void transpose_kernel(const float* __restrict__ x,
                                                        ushort_t* __restrict__ x_t) {
    __shared__ uint_t tlds[256 * 33];
    int tid = threadIdx.x;
    int b = blockIdx.x / 144;
    int p0 = (blockIdx.x % 144) * 256;
    ushort_t* ts = (ushort_t*)tlds;
    for (int c = 0; c < 64; ++c) {
        float v = x[((size_t)(b * 64 + c)) * HW + p0 + tid];
        ts[tid * 66 + c] = f2bf(v);
    }
    __syncthreads();
#pragma unroll
    for (int j = 0; j < 8; ++j) {
        int chunk = j * 256 + tid;
        int pl = chunk >> 3, s = chunk & 7;
        int bd = pl * 33 + s * 4;
        u32x4 v = {tlds[bd], tlds[bd + 1], tlds[bd + 2], tlds[bd + 3]};
        ((u32x4*)x_t)[(size_t)(b * HW + p0) * 8 + chunk] = v;
    }
}

// ============ helpers for fused deform ============
__device__ __forceinline__ void corner_setup(const float* off_lds, int ploc, int tap,
                                             int ybase, int xbase, int* idx, float* w) {
    float ody = off_lds[ploc * 19 + 2 * tap];
    float odx = off_lds[ploc * 19 + 2 * tap + 1];
    float py = (float)ybase + ody;
    float px = (float)xbase + odx;
    float fy = floorf(py), fx = floorf(px);
    int y0 = (int)fy, x0 = (int)fx;
    float wy = py - fy, wx = px - fx;
    int y0c = min(max(y0, 0), H_ - 1), y1c = min(max(y0 + 1, 0), H_ - 1);
    int x0c = min(max(x0, 0), W_ - 1), x1c = min(max(x0 + 1, 0), W_ - 1);
    float vy0 = (y0 >= 0 && y0 < H_) ? 1.f : 0.f;
    float vy1 = (y0 + 1 >= 0 && y0 + 1 < H_) ? 1.f : 0.f;
    float vx0 = (x0 >= 0 && x0 < W_) ? 1.f : 0.f;
    float vx1 = (x0 + 1 >= 0 && x0 + 1 < W_) ? 1.f : 0.f;
    w[0] = (1.f - wy) * (1.f - wx) * vy0 * vx0;
    w[1] = (1.f - wy) * wx * vy0 * vx1;
    w[2] = wy * (1.f - wx) * vy1 * vx0;
    w[3] = wy * wx * vy1 * vx1;
    idx[0] = (y0c * W_ + x0c) * 64; idx[1] = (y0c * W_ + x1c) * 64;
    idx[2] = (y1c * W_ + x0c) * 64; idx[3] = (y1c * W_ + x1c) * 64;
}

__device__ __forceinline__ short8 interp_frag(const ushort_t* base, const int* idx,
                                              const float* w) {
    u32x4 c0 = *(const u32x4*)(base + idx[0]);
    u32x4 c1 = *(const u32x4*)(base + idx[1]);
    u32x4 c2 = *(const u32x4*)(base + idx[2]);
    u32x4 c3 = *(const u32x4*)(base + idx[3]);
    short8 r;
#pragma unroll
    for (int q = 0; q < 4; ++q) {
        float lo = w[0] * bflo(c0[q]) + w[1] * bflo(c1[q]) + w[2] * bflo(c2[q]) + w[3] * bflo(c3[q]);
        float hi = w[0] * bfhi(c0[q]) + w[1] * bfhi(c1[q]) + w[2] * bfhi(c2[q]) + w[3] * bfhi(c3[q]);
        uint_t p = (uint_t)f2bf(lo) | ((uint_t)f2bf(hi) << 16);
        ((uint_t*)&r)[q] = p;
    }
    return r;
}

// ============ K2: fused offset-conv + deformable conv (64-pos tiles) ============
// Block = 64 positions, 4 waves; wave owns 16 positions (one N-fragment).
__global__ __launch_bounds__(256) void deform_fused_kernel(
    const ushort_t* __restrict__ x_t, const ushort_t* __restrict__ w_off,
    const float* __restrict__ ob, const ushort_t* __restrict__ w_bf,
    const float* __restrict__ scale_g, const float* __restrict__ shift_g,
    float* __restrict__ out, float* __restrict__ partial) {
    __shared__ float off_lds[64 * 19];
    __shared__ float red[256];

    int tid = threadIdx.x;
    int tile = (blockIdx.x & 7) * 288 + (blockIdx.x >> 3);   // XCD-bijective (2304 % 8 == 0)
    int b = tile / 576;
    int p0 = (tile % 576) * 64;

    int wid = tid >> 6, lane = tid & 63, ln = lane & 15, kg = lane >> 4;
    int pA_loc = wid * 16 + ln;
    int pA = p0 + pA_loc;
    int yA = pA / 192, xA = pA - yA * 192;
    const ushort_t* xt_b = x_t + (size_t)b * (HW * 64);

    // ---- phase 0: offset conv (M=32, rows 0..17 used) ----
    f32x4 ao[2];
#pragma unroll
    for (int i = 0; i < 2; ++i) ao[i] = (f32x4){0.f, 0.f, 0.f, 0.f};

    for (int tap = 0; tap < 9; ++tap) {
        int ti = tap / 3 - 1, tj = tap % 3 - 1;
        short8 bA[2];
        {
            int yy = yA + ti, xx = xA + tj;
            bool v = (yy >= 0 && yy < H_ && xx >= 0 && xx < W_);
            int base = (min(max(yy, 0), H_ - 1) * W_ + min(max(xx, 0), W_ - 1)) * 64;
#pragma unroll
            for (int ks = 0; ks < 2; ++ks) {
                short8 t8 = *(const short8*)(xt_b + base + ks * 32 + kg * 8);
                bA[ks] = v ? t8 : zero8();
            }
        }
        const ushort_t* wt = w_off + tap * 2048;
#pragma unroll
        for (int ks = 0; ks < 2; ++ks) {
            int ch = ks * 32 + kg * 8;
            short8 a0 = *(const short8*)(wt + ln * 64 + ch);
            short8 a1 = *(const short8*)(wt + (16 + ln) * 64 + ch);
            ao[0] = __builtin_amdgcn_mfma_f32_16x16x32_bf16(a0, bA[ks], ao[0], 0, 0, 0);
            ao[1] = __builtin_amdgcn_mfma_f32_16x16x32_bf16(a1, bA[ks], ao[1], 0, 0, 0);
        }
    }
#pragma unroll
    for (int mt = 0; mt < 2; ++mt)
#pragma unroll
        for (int r = 0; r < 4; ++r) {
            int m = mt * 16 + kg * 4 + r;
            if (m < 18)
                off_lds[pA_loc * 19 + m] = ao[mt][r] + ob[m];
        }
    __syncthreads();

    // ---- main: deformable conv ----
    f32x4 acc[4];
#pragma unroll
    for (int mt = 0; mt < 4; ++mt) acc[mt] = (f32x4){0.f, 0.f, 0.f, 0.f};

    for (int tap = 0; tap < 9; ++tap) {
        int ti = tap / 3 - 1, tj = tap % 3 - 1;
        int iA[4];
        float wA[4];
        corner_setup(off_lds, pA_loc, tap, yA + ti, xA + tj, iA, wA);
        const ushort_t* wt = w_bf + tap * 4096;
#pragma unroll
        for (int ks = 0; ks < 2; ++ks) {
            int ch = ks * 32 + kg * 8;
            short8 fA = interp_frag(xt_b + ch, iA, wA);
            short8 a0 = *(const short8*)(wt + (0 + ln) * 64 + ch);
            short8 a1 = *(const short8*)(wt + (16 + ln) * 64 + ch);
            short8 a2 = *(const short8*)(wt + (32 + ln) * 64 + ch);
            short8 a3 = *(const short8*)(wt + (48 + ln) * 64 + ch);
            acc[0] = __builtin_amdgcn_mfma_f32_16x16x32_bf16(a0, fA, acc[0], 0, 0, 0);
            acc[1] = __builtin_amdgcn_mfma_f32_16x16x32_bf16(a1, fA, acc[1], 0, 0, 0);
            acc[2] = __builtin_amdgcn_mfma_f32_16x16x32_bf16(a2, fA, acc[2], 0, 0, 0);
            acc[3] = __builtin_amdgcn_mfma_f32_16x16x32_bf16(a3, fA, acc[3], 0, 0, 0);
        }
    }

    // ---- epilogue: BN affine, store, per-channel partial sums ----
#pragma unroll
    for (int mt = 0; mt < 4; ++mt) {
#pragma unroll
        for (int r = 0; r < 4; ++r) {
            int m = mt * 16 + kg * 4 + r;
            float sc = scale_g[m], sh = shift_g[m];
            float v0 = acc[mt][r] * sc + sh;
            out[(size_t)(b * 64 + m) * HW + pA] = v0;
            float vs = v0;
            vs += __shfl_xor(vs, 1, 16);
            vs += __shfl_xor(vs, 2, 16);
            vs += __shfl_xor(vs, 4, 16);
            vs += __shfl_xor(vs, 8, 16);
            if (ln == 0) red[m * 4 + wid] = vs;
        }
    }
    __syncthreads();
    if (tid < 64)
        partial[tid * 2304 + tile] = red[tid * 4 + 0] + red[tid * 4 + 1] +
                                     red[tid * 4 + 2] + red[tid * 4 + 3];
}

// ============ KR: parallel partial reduce -> pooled mean ============
__global__ void reduce_kernel(const float* __restrict__ partial, float* __restrict__ pooled) {
    int o = blockIdx.x & 63, b = blockIdx.x >> 6;
    const float* pr = partial + o * 2304 + b * 576;
    int t = threadIdx.x;
    float s = 0.f;
    for (int q = t; q < 576; q += 64) s += pr[q];
#pragma unroll
    for (int d = 1; d < 64; d <<= 1) s += __shfl_xor(s, d, 64);
    if (t == 0) pooled[b * 64 + o] = s * (1.0f / (float)HW);
}

// ============ K3: SE MLP -> cw; per-batch bf16 tap-GEMM weights ============
__global__ void ca_kernel(const float* __restrict__ pooled_g,
                          const float* __restrict__ w1, const float* __restrict__ b1,
                          const float* __restrict__ w2, const float* __restrict__ b2,
                          const float* __restrict__ saw, float* __restrict__ cw,
                          ushort_t* __restrict__ we_bf) {
    __shared__ float pooled[256];
    __shared__ float t1[16];
    int t = threadIdx.x;
    int b = t >> 6, o = t & 63;
    pooled[t] = pooled_g[t];
    __syncthreads();
    if (t < 16) {
        int bb = t >> 2, hh = t & 3;
        float a = b1[hh];
        for (int c = 0; c < 64; ++c) a += pooled[bb * 64 + c] * w1[hh * 64 + c];
        t1[t] = fmaxf(a, 0.f);
    }
    __syncthreads();
    float a = b2[o];
#pragma unroll
    for (int h2 = 0; h2 < 4; ++h2) a += t1[b * 4 + h2] * w2[o * 4 + h2];
    float cwv = 1.f / (1.f + __expf(-a));
    cw[t] = cwv;
    for (int tap = 0; tap < 64; ++tap) {
        float v = (tap < 49) ? cwv * saw[o * 49 + tap] : 0.f;
        we_bf[(b * 64 + tap) * 64 + o] = f2bf(v);
    }
}

// ============ K4a: tap GEMM  u[b][t][p] = sum_c we_bf[b][t][c] * h[b][c][p] ============
__global__ __launch_bounds__(256) void tap_gemm_kernel(
    const float* __restrict__ h, const ushort_t* __restrict__ we_bf,
    ushort_t* __restrict__ u) {
    int tid = threadIdx.x;
    int b = blockIdx.y;
    int p0 = blockIdx.x * 128;
    int wid = tid >> 6, lane = tid & 63, ln = lane & 15, kg = lane >> 4;
    int pA = p0 + wid * 32 + ln, pB = pA + 16;
    const float* hb = h + (size_t)b * 64 * HW;
    const ushort_t* wt = we_bf + b * 4096;

    f32x4 acc[4][2];
#pragma unroll
    for (int mt = 0; mt < 4; ++mt)
#pragma unroll
        for (int nt = 0; nt < 2; ++nt) acc[mt][nt] = (f32x4){0.f, 0.f, 0.f, 0.f};

#pragma unroll
    for (int ks = 0; ks < 2; ++ks) {
        int ch = ks * 32 + kg * 8;
        short8 fA, fB;
#pragma unroll
        for (int q = 0; q < 8; ++q) {
            fA[q] = (short)f2bf(hb[(size_t)(ch + q) * HW + pA]);
            fB[q] = (short)f2bf(hb[(size_t)(ch + q) * HW + pB]);
        }
        short8 a0 = *(const short8*)(wt + (0 + ln) * 64 + ch);
        short8 a1 = *(const short8*)(wt + (16 + ln) * 64 + ch);
        short8 a2 = *(const short8*)(wt + (32 + ln) * 64 + ch);
        short8 a3 = *(const short8*)(wt + (48 + ln) * 64 + ch);
        acc[0][0] = __builtin_amdgcn_mfma_f32_16x16x32_bf16(a0, fA, acc[0][0], 0, 0, 0);
        acc[0][1] = __builtin_amdgcn_mfma_f32_16x16x32_bf16(a0, fB, acc[0][1], 0, 0, 0);
        acc[1][0] = __builtin_amdgcn_mfma_f32_16x16x32_bf16(a1, fA, acc[1][0], 0, 0, 0);
        acc[1][1] = __builtin_amdgcn_mfma_f32_16x16x32_bf16(a1, fB, acc[1][1], 0, 0, 0);
        acc[2][0] = __builtin_amdgcn_mfma_f32_16x16x32_bf16(a2, fA, acc[2][0], 0, 0, 0);
        acc[2][1] = __builtin_amdgcn_mfma_f32_16x16x32_bf16(a2, fB, acc[2][1], 0, 0, 0);
        acc[3][0] = __builtin_amdgcn_mfma_f32_16x16x32_bf16(a3, fA, acc[3][0], 0, 0, 0);
        acc[3][1] = __builtin_amdgcn_mfma_f32_16x16x32_bf16(a3, fB, acc[3][1], 0, 0, 0);
    }
#pragma unroll
    for (int mt = 0; mt < 4; ++mt)
#pragma unroll
        for (int r = 0; r < 4; ++r) {
            int m = mt * 16 + kg * 4 + r;
            if (m < 49) {
                ushort_t* up = u + (size_t)(b * 49 + m) * HW;
                up[pA] = f2bf(acc[mt][0][r]);
                up[pB] = f2bf(acc[mt][1][r]);
            }
        }
}

// ============ K4b: shift-add 49 taps -> sigmoid -> out *= cw*sw (fused final) ============
__global__ __launch_bounds__(256) void sa_final_kernel(
    float* __restrict__ out, const ushort_t* __restrict__ u,
    const float* __restrict__ cw, const float* __restrict__ sab) {
    __shared__ float cw_l[64];
    int tid = threadIdx.x;
    int b = blockIdx.y;
    int p = blockIdx.x * 256 + tid;
    if (tid < 64) cw_l[tid] = cw[b * 64 + tid];
    __syncthreads();
    int y = p / 192, x = p - y * 192;
    float s = sab[0];
    const ushort_t* ub = u + (size_t)b * 49 * HW;
#pragma unroll
    for (int dy = 0; dy < 7; ++dy)
#pragma unroll
        for (int dx = 0; dx < 7; ++dx) {
            int yy = y + dy - 3, xx = x + dx - 3;
            bool ok = ((unsigned)yy < 192u) && ((unsigned)xx < 192u);
            int ad = ok ? (p + (dy - 3) * 192 + (dx - 3)) : 0;
            float v = bflo((uint_t)ub[(size_t)(dy * 7 + dx) * HW + ad]);
            s += ok ? v : 0.f;
        }
    float swv = 1.f / (1.f + __expf(-s));
#pragma unroll 8
    for (int c = 0; c < 64; ++c) {
        size_t ix = (size_t)(b * 64 + c) * HW + p;
        out[ix] = out[ix] * (cw_l[c] * swv);
    }
}

extern "C" void kernel_launch(void* const* d_in, const int* in_sizes, int n_in,
                              void* d_out, int out_size, void* d_ws, size_t ws_size,
                              hipStream_t stream) {
    const float* x     = (const float*)d_in[0];
    const float* off_w = (const float*)d_in[1];
    const float* off_b = (const float*)d_in[2];
    const float* dw    = (const float*)d_in[3];
    const float* db    = (const float*)d_in[4];
    const float* bn_g  = (const float*)d_in[5];
    const float* bn_b  = (const float*)d_in[6];
    const float* bn_m  = (const float*)d_in[7];
    const float* bn_v  = (const float*)d_in[8];
    const float* ca_w1 = (const float*)d_in[9];
    const float* ca_b1 = (const float*)d_in[10];
    const float* ca_w2 = (const float*)d_in[11];
    const float* ca_b2 = (const float*)d_in[12];
    const float* sa_w  = (const float*)d_in[13];
    const float* sa_b  = (const float*)d_in[14];
    float* out = (float*)d_out;
    float* ws  = (float*)d_ws;

    // ws layout (floats):
    // x_t  [B,HW,64] bf16   @ 0        (9437184 sh = 4718592 fl)
    //   u  [B,49,HW] bf16   @ 0        (aliases x_t; x_t dead after deform)
    // w_bf                  @ 4718592  (18432 sh)
    // w_off                 @ 4737024  (18432 sh)
    // scale @4746240  shift @4746304  cw @4746368  pooled @4746624
    // partial [64][2304]    @ 4746880  (147456 fl)
    // we_bf [B][64][64] sh  @ 4894336  (16384 sh = 8192 fl)  -> end 4902528 fl = 19.6 MB
    ushort_t* x_t    = (ushort_t*)ws;
    ushort_t* u      = (ushort_t*)ws;
    ushort_t* w_bf   = (ushort_t*)(ws + 4718592);
    ushort_t* w_off  = (ushort_t*)(ws + 4737024);
    float* scale     = ws + 4746240;
    float* shift     = ws + 4746304;
    float* cw        = ws + 4746368;
    float* pooled    = ws + 4746624;
    float* partial   = ws + 4746880;
    ushort_t* we_bf  = (ushort_t*)(ws + 4894336);

    prep_kernel<<<216, 256, 0, stream>>>(dw, db, bn_g, bn_b, bn_m, bn_v, off_w,
                                         w_bf, w_off, scale, shift);
    transpose_kernel<<<576, 256, 0, stream>>>(x, x_t);
    deform_fused_kernel<<<2304, 256, 0, stream>>>(x_t, w_off, off_b, w_bf,
                                                  scale, shift, out, partial);
    reduce_kernel<<<256, 64, 0, stream>>>(partial, pooled);
    ca_kernel<<<1, 256, 0, stream>>>(pooled, ca_w1, ca_b1, ca_w2, ca_b2, sa_w, cw, we_bf);
    tap_gemm_kernel<<<dim3(288, 4), 256, 0, stream>>>(out, we_bf, u);
    sa_final_kernel<<<dim3(144, 4), 256, 0, stream>>>(out, u, cw, sa_b);
}

// Round 6
// 256.532 us; speedup vs baseline: 1.1615x; 1.1615x over previous
//
#include <hip/hip_runtime.h>

#define H_  192
#define W_  192
#define HW  36864
#define B_  4

typedef __attribute__((ext_vector_type(8))) short short8;
typedef __attribute__((ext_vector_type(4))) float f32x4;
typedef __attribute__((ext_vector_type(4))) unsigned int u32x4;
typedef unsigned short ushort_t;
typedef unsigned int uint_t;

__device__ __forceinline__ ushort_t f2bf(float v) {
    uint_t u = __builtin_bit_cast(uint_t, v);
    u += 0x7FFFu + ((u >> 16) & 1u);   // RNE
    return (ushort_t)(u >> 16);
}
__device__ __forceinline__ float bflo(uint_t u) {
    uint_t w = u << 16; return __builtin_bit_cast(float, w);
}
__device__ __forceinline__ float bfhi(uint_t u) {
    uint_t w = u & 0xFFFF0000u; return __builtin_bit_cast(float, w);
}
__device__ __forceinline__ uint_t cvt_pk_bf16(float lo, float hi) {
    uint_t r;
    asm("v_cvt_pk_bf16_f32 %0, %1, %2" : "=v"(r) : "v"(lo), "v"(hi));
    return r;
}
__device__ __forceinline__ short8 zero8() {
    u32x4 z = {0u, 0u, 0u, 0u};
    return __builtin_bit_cast(short8, z);
}

// ============ K0: weight prep ============
__global__ void prep_kernel(const float* __restrict__ dw, const float* __restrict__ db,
                            const float* __restrict__ g, const float* __restrict__ be,
                            const float* __restrict__ mu, const float* __restrict__ var,
                            const float* __restrict__ ow,
                            ushort_t* __restrict__ w_bf, ushort_t* __restrict__ w_off,
                            float* __restrict__ scale, float* __restrict__ shift) {
    int idx = blockIdx.x * 256 + threadIdx.x;
    if (idx < 36864) {
        int tap = idx >> 12, o = (idx >> 6) & 63, c = idx & 63;
        w_bf[idx] = f2bf(dw[(o * 64 + c) * 9 + tap]);
    }
    int idx2 = idx - 36864;
    if (idx2 >= 0 && idx2 < 18432) {
        int tap = idx2 >> 11, o = (idx2 >> 6) & 31, c = idx2 & 63;
        w_off[idx2] = (o < 18) ? f2bf(ow[(o * 64 + c) * 9 + tap]) : (ushort_t)0;
    }
    if (idx < 64) {
        float s = g[idx] * rsqrtf(var[idx] + 1e-5f);
        scale[idx] = s;
        shift[idx] = (db[idx] - mu[idx]) * s + be[idx];
    }
}

// ============ KT: x [B,C,HW] f32 -> x_t [B,HW,C] bf16 ============
__global__ __launch_bounds__(256) void transpose_kernel(const float* __restrict__ x,
                                                        ushort_t* __restrict__ x_t) {
    __shared__ uint_t tlds[256 * 33];
    int tid = threadIdx.x;
    int b = blockIdx.x / 144;
    int p0 = (blockIdx.x % 144) * 256;
    ushort_t* ts = (ushort_t*)tlds;
    for (int c = 0; c < 64; ++c) {
        float v = x[((size_t)(b * 64 + c)) * HW + p0 + tid];
        ts[tid * 66 + c] = f2bf(v);
    }
    __syncthreads();
#pragma unroll
    for (int j = 0; j < 8; ++j) {
        int chunk = j * 256 + tid;
        int pl = chunk >> 3, s = chunk & 7;
        int bd = pl * 33 + s * 4;
        u32x4 v = {tlds[bd], tlds[bd + 1], tlds[bd + 2], tlds[bd + 3]};
        ((u32x4*)x_t)[(size_t)(b * HW + p0) * 8 + chunk] = v;
    }
}

// ============ helpers for fused deform ============
__device__ __forceinline__ void corner_setup(const float* off_lds, int ploc, int tap,
                                             int ybase, int xbase, int* idx, float* w) {
    float ody = off_lds[ploc * 19 + 2 * tap];
    float odx = off_lds[ploc * 19 + 2 * tap + 1];
    float py = (float)ybase + ody;
    float px = (float)xbase + odx;
    float fy = floorf(py), fx = floorf(px);
    int y0 = (int)fy, x0 = (int)fx;
    float wy = py - fy, wx = px - fx;
    int y0c = min(max(y0, 0), H_ - 1), y1c = min(max(y0 + 1, 0), H_ - 1);
    int x0c = min(max(x0, 0), W_ - 1), x1c = min(max(x0 + 1, 0), W_ - 1);
    float vy0 = (y0 >= 0 && y0 < H_) ? 1.f : 0.f;
    float vy1 = (y0 + 1 >= 0 && y0 + 1 < H_) ? 1.f : 0.f;
    float vx0 = (x0 >= 0 && x0 < W_) ? 1.f : 0.f;
    float vx1 = (x0 + 1 >= 0 && x0 + 1 < W_) ? 1.f : 0.f;
    w[0] = (1.f - wy) * (1.f - wx) * vy0 * vx0;
    w[1] = (1.f - wy) * wx * vy0 * vx1;
    w[2] = wy * (1.f - wx) * vy1 * vx0;
    w[3] = wy * wx * vy1 * vx1;
    idx[0] = (y0c * W_ + x0c) * 64; idx[1] = (y0c * W_ + x1c) * 64;
    idx[2] = (y1c * W_ + x0c) * 64; idx[3] = (y1c * W_ + x1c) * 64;
}

__device__ __forceinline__ void load_corners(const ushort_t* base, const int* idx,
                                             u32x4* buf) {
    buf[0] = *(const u32x4*)(base + idx[0]);
    buf[1] = *(const u32x4*)(base + idx[1]);
    buf[2] = *(const u32x4*)(base + idx[2]);
    buf[3] = *(const u32x4*)(base + idx[3]);
}

__device__ __forceinline__ short8 interp_compute(const u32x4* buf, const float* w) {
    short8 r;
#pragma unroll
    for (int q = 0; q < 4; ++q) {
        float lo = w[0] * bflo(buf[0][q]) + w[1] * bflo(buf[1][q]) +
                   w[2] * bflo(buf[2][q]) + w[3] * bflo(buf[3][q]);
        float hi = w[0] * bfhi(buf[0][q]) + w[1] * bfhi(buf[1][q]) +
                   w[2] * bfhi(buf[2][q]) + w[3] * bfhi(buf[3][q]);
        ((uint_t*)&r)[q] = cvt_pk_bf16(lo, hi);
    }
    return r;
}

// ============ K2: fused offset-conv + deformable conv (128-pos tiles) ============
__global__ __launch_bounds__(256) void deform_fused_kernel(
    const ushort_t* __restrict__ x_t, const ushort_t* __restrict__ w_off,
    const float* __restrict__ ob, const ushort_t* __restrict__ w_bf,
    const float* __restrict__ scale_g, const float* __restrict__ shift_g,
    float* __restrict__ out, float* __restrict__ partial) {
    __shared__ float off_lds[128 * 19];
    __shared__ float red[256];

    int tid = threadIdx.x;
    int tile = (blockIdx.x & 7) * 144 + (blockIdx.x >> 3);   // XCD-bijective
    int b = tile / 288;
    int p0 = (tile % 288) * 128;

    int wid = tid >> 6, lane = tid & 63, ln = lane & 15, kg = lane >> 4;
    int pA_loc = wid * 32 + ln, pB_loc = pA_loc + 16;
    int pA = p0 + pA_loc, pB = p0 + pB_loc;
    int yA = pA / 192, xA = pA - yA * 192;
    int yB = pB / 192, xB = pB - yB * 192;
    const ushort_t* xt_b = x_t + (size_t)b * (HW * 64);

    // ---- phase 0: offset conv ----
    f32x4 ao[2][2];
#pragma unroll
    for (int i = 0; i < 2; ++i)
#pragma unroll
        for (int j = 0; j < 2; ++j) ao[i][j] = (f32x4){0.f, 0.f, 0.f, 0.f};

    for (int tap = 0; tap < 9; ++tap) {
        int ti = tap / 3 - 1, tj = tap % 3 - 1;
        short8 bA[2], bB[2];
        {
            int yy = yA + ti, xx = xA + tj;
            bool v = (yy >= 0 && yy < H_ && xx >= 0 && xx < W_);
            int base = (min(max(yy, 0), H_ - 1) * W_ + min(max(xx, 0), W_ - 1)) * 64;
#pragma unroll
            for (int ks = 0; ks < 2; ++ks) {
                short8 t8 = *(const short8*)(xt_b + base + ks * 32 + kg * 8);
                bA[ks] = v ? t8 : zero8();
            }
        }
        {
            int yy = yB + ti, xx = xB + tj;
            bool v = (yy >= 0 && yy < H_ && xx >= 0 && xx < W_);
            int base = (min(max(yy, 0), H_ - 1) * W_ + min(max(xx, 0), W_ - 1)) * 64;
#pragma unroll
            for (int ks = 0; ks < 2; ++ks) {
                short8 t8 = *(const short8*)(xt_b + base + ks * 32 + kg * 8);
                bB[ks] = v ? t8 : zero8();
            }
        }
        const ushort_t* wt = w_off + tap * 2048;
#pragma unroll
        for (int ks = 0; ks < 2; ++ks) {
            int ch = ks * 32 + kg * 8;
            short8 a0 = *(const short8*)(wt + ln * 64 + ch);
            short8 a1 = *(const short8*)(wt + (16 + ln) * 64 + ch);
            ao[0][0] = __builtin_amdgcn_mfma_f32_16x16x32_bf16(a0, bA[ks], ao[0][0], 0, 0, 0);
            ao[0][1] = __builtin_amdgcn_mfma_f32_16x16x32_bf16(a0, bB[ks], ao[0][1], 0, 0, 0);
            ao[1][0] = __builtin_amdgcn_mfma_f32_16x16x32_bf16(a1, bA[ks], ao[1][0], 0, 0, 0);
            ao[1][1] = __builtin_amdgcn_mfma_f32_16x16x32_bf16(a1, bB[ks], ao[1][1], 0, 0, 0);
        }
    }
#pragma unroll
    for (int mt = 0; mt < 2; ++mt)
#pragma unroll
        for (int r = 0; r < 4; ++r) {
            int m = mt * 16 + kg * 4 + r;
            if (m < 18) {
                float bias = ob[m];
                off_lds[pA_loc * 19 + m] = ao[mt][0][r] + bias;
                off_lds[pB_loc * 19 + m] = ao[mt][1][r] + bias;
            }
        }
    __syncthreads();

    // ---- main: deformable conv; all 16 gather loads issued before interp ----
    f32x4 acc[4][2];
#pragma unroll
    for (int mt = 0; mt < 4; ++mt)
#pragma unroll
        for (int nt = 0; nt < 2; ++nt) acc[mt][nt] = (f32x4){0.f, 0.f, 0.f, 0.f};

#pragma unroll 3
    for (int tap = 0; tap < 9; ++tap) {
        int ti = tap / 3 - 1, tj = tap % 3 - 1;
        int iA[4], iB[4];
        float wA[4], wB[4];
        corner_setup(off_lds, pA_loc, tap, yA + ti, xA + tj, iA, wA);
        corner_setup(off_lds, pB_loc, tap, yB + ti, xB + tj, iB, wB);

        u32x4 bufA0[4], bufA1[4], bufB0[4], bufB1[4];
        load_corners(xt_b + kg * 8, iA, bufA0);
        load_corners(xt_b + 32 + kg * 8, iA, bufA1);
        load_corners(xt_b + kg * 8, iB, bufB0);
        load_corners(xt_b + 32 + kg * 8, iB, bufB1);

        const ushort_t* wt = w_bf + tap * 4096;
        short8 a00 = *(const short8*)(wt + (0 + ln) * 64 + kg * 8);
        short8 a01 = *(const short8*)(wt + (16 + ln) * 64 + kg * 8);
        short8 a02 = *(const short8*)(wt + (32 + ln) * 64 + kg * 8);
        short8 a03 = *(const short8*)(wt + (48 + ln) * 64 + kg * 8);
        short8 a10 = *(const short8*)(wt + (0 + ln) * 64 + 32 + kg * 8);
        short8 a11 = *(const short8*)(wt + (16 + ln) * 64 + 32 + kg * 8);
        short8 a12 = *(const short8*)(wt + (32 + ln) * 64 + 32 + kg * 8);
        short8 a13 = *(const short8*)(wt + (48 + ln) * 64 + 32 + kg * 8);

        short8 fA0 = interp_compute(bufA0, wA);
        short8 fB0 = interp_compute(bufB0, wB);
        acc[0][0] = __builtin_amdgcn_mfma_f32_16x16x32_bf16(a00, fA0, acc[0][0], 0, 0, 0);
        acc[0][1] = __builtin_amdgcn_mfma_f32_16x16x32_bf16(a00, fB0, acc[0][1], 0, 0, 0);
        acc[1][0] = __builtin_amdgcn_mfma_f32_16x16x32_bf16(a01, fA0, acc[1][0], 0, 0, 0);
        acc[1][1] = __builtin_amdgcn_mfma_f32_16x16x32_bf16(a01, fB0, acc[1][1], 0, 0, 0);
        acc[2][0] = __builtin_amdgcn_mfma_f32_16x16x32_bf16(a02, fA0, acc[2][0], 0, 0, 0);
        acc[2][1] = __builtin_amdgcn_mfma_f32_16x16x32_bf16(a02, fB0, acc[2][1], 0, 0, 0);
        acc[3][0] = __builtin_amdgcn_mfma_f32_16x16x32_bf16(a03, fA0, acc[3][0], 0, 0, 0);
        acc[3][1] = __builtin_amdgcn_mfma_f32_16x16x32_bf16(a03, fB0, acc[3][1], 0, 0, 0);

        short8 fA1 = interp_compute(bufA1, wA);
        short8 fB1 = interp_compute(bufB1, wB);
        acc[0][0] = __builtin_amdgcn_mfma_f32_16x16x32_bf16(a10, fA1, acc[0][0], 0, 0, 0);
        acc[0][1] = __builtin_amdgcn_mfma_f32_16x16x32_bf16(a10, fB1, acc[0][1], 0, 0, 0);
        acc[1][0] = __builtin_amdgcn_mfma_f32_16x16x32_bf16(a11, fA1, acc[1][0], 0, 0, 0);
        acc[1][1] = __builtin_amdgcn_mfma_f32_16x16x32_bf16(a11, fB1, acc[1][1], 0, 0, 0);
        acc[2][0] = __builtin_amdgcn_mfma_f32_16x16x32_bf16(a12, fA1, acc[2][0], 0, 0, 0);
        acc[2][1] = __builtin_amdgcn_mfma_f32_16x16x32_bf16(a12, fB1, acc[2][1], 0, 0, 0);
        acc[3][0] = __builtin_amdgcn_mfma_f32_16x16x32_bf16(a13, fA1, acc[3][0], 0, 0, 0);
        acc[3][1] = __builtin_amdgcn_mfma_f32_16x16x32_bf16(a13, fB1, acc[3][1], 0, 0, 0);
    }

    // ---- epilogue: BN affine, store, per-channel partial sums ----
#pragma unroll
    for (int mt = 0; mt < 4; ++mt) {
#pragma unroll
        for (int r = 0; r < 4; ++r) {
            int m = mt * 16 + kg * 4 + r;
            float sc = scale_g[m], sh = shift_g[m];
            float v0 = acc[mt][0][r] * sc + sh;
            float v1 = acc[mt][1][r] * sc + sh;
            size_t orow = (size_t)(b * 64 + m) * HW + p0 + wid * 32 + ln;
            out[orow] = v0;
            out[orow + 16] = v1;
            float vs = v0 + v1;
            vs += __shfl_xor(vs, 1, 16);
            vs += __shfl_xor(vs, 2, 16);
            vs += __shfl_xor(vs, 4, 16);
            vs += __shfl_xor(vs, 8, 16);
            if (ln == 0) red[m * 4 + wid] = vs;
        }
    }
    __syncthreads();
    if (tid < 64)
        partial[tid * 1152 + tile] = red[tid * 4 + 0] + red[tid * 4 + 1] +
                                     red[tid * 4 + 2] + red[tid * 4 + 3];
}

// ============ KR: parallel partial reduce -> pooled mean ============
__global__ void reduce_kernel(const float* __restrict__ partial, float* __restrict__ pooled) {
    int o = blockIdx.x & 63, b = blockIdx.x >> 6;
    const float* pr = partial + o * 1152 + b * 288;
    int t = threadIdx.x;
    float s = 0.f;
    for (int q = t; q < 288; q += 64) s += pr[q];
#pragma unroll
    for (int d = 1; d < 64; d <<= 1) s += __shfl_xor(s, d, 64);
    if (t == 0) pooled[b * 64 + o] = s * (1.0f / (float)HW);
}

// ============ K3: SE MLP -> cw; per-batch bf16 tap-GEMM weights ============
__global__ void ca_kernel(const float* __restrict__ pooled_g,
                          const float* __restrict__ w1, const float* __restrict__ b1,
                          const float* __restrict__ w2, const float* __restrict__ b2,
                          const float* __restrict__ saw, float* __restrict__ cw,
                          ushort_t* __restrict__ we_bf) {
    __shared__ float pooled[256];
    __shared__ float t1[16];
    int t = threadIdx.x;
    int b = t >> 6, o = t & 63;
    pooled[t] = pooled_g[t];
    __syncthreads();
    if (t < 16) {
        int bb = t >> 2, hh = t & 3;
        float a = b1[hh];
        for (int c = 0; c < 64; ++c) a += pooled[bb * 64 + c] * w1[hh * 64 + c];
        t1[t] = fmaxf(a, 0.f);
    }
    __syncthreads();
    float a = b2[o];
#pragma unroll
    for (int h2 = 0; h2 < 4; ++h2) a += t1[b * 4 + h2] * w2[o * 4 + h2];
    float cwv = 1.f / (1.f + __expf(-a));
    cw[t] = cwv;
    for (int tap = 0; tap < 64; ++tap) {
        float v = (tap < 49) ? cwv * saw[o * 49 + tap] : 0.f;
        we_bf[(b * 64 + tap) * 64 + o] = f2bf(v);
    }
}

// ============ K4a: tap GEMM  u[b][t][p] = sum_c we_bf[b][t][c] * h[b][c][p] ============
__global__ __launch_bounds__(256) void tap_gemm_kernel(
    const float* __restrict__ h, const ushort_t* __restrict__ we_bf,
    ushort_t* __restrict__ u) {
    int tid = threadIdx.x;
    int b = blockIdx.y;
    int p0 = blockIdx.x * 128;
    int wid = tid >> 6, lane = tid & 63, ln = lane & 15, kg = lane >> 4;
    int pA = p0 + wid * 32 + ln, pB = pA + 16;
    const float* hb = h + (size_t)b * 64 * HW;
    const ushort_t* wt = we_bf + b * 4096;

    f32x4 acc[4][2];
#pragma unroll
    for (int mt = 0; mt < 4; ++mt)
#pragma unroll
        for (int nt = 0; nt < 2; ++nt) acc[mt][nt] = (f32x4){0.f, 0.f, 0.f, 0.f};

#pragma unroll
    for (int ks = 0; ks < 2; ++ks) {
        int ch = ks * 32 + kg * 8;
        short8 fA, fB;
#pragma unroll
        for (int q = 0; q < 4; ++q) {
            float a0 = hb[(size_t)(ch + 2 * q) * HW + pA];
            float a1 = hb[(size_t)(ch + 2 * q + 1) * HW + pA];
            float b0 = hb[(size_t)(ch + 2 * q) * HW + pB];
            float b1 = hb[(size_t)(ch + 2 * q + 1) * HW + pB];
            ((uint_t*)&fA)[q] = cvt_pk_bf16(a0, a1);
            ((uint_t*)&fB)[q] = cvt_pk_bf16(b0, b1);
        }
        short8 a0 = *(const short8*)(wt + (0 + ln) * 64 + ch);
        short8 a1 = *(const short8*)(wt + (16 + ln) * 64 + ch);
        short8 a2 = *(const short8*)(wt + (32 + ln) * 64 + ch);
        short8 a3 = *(const short8*)(wt + (48 + ln) * 64 + ch);
        acc[0][0] = __builtin_amdgcn_mfma_f32_16x16x32_bf16(a0, fA, acc[0][0], 0, 0, 0);
        acc[0][1] = __builtin_amdgcn_mfma_f32_16x16x32_bf16(a0, fB, acc[0][1], 0, 0, 0);
        acc[1][0] = __builtin_amdgcn_mfma_f32_16x16x32_bf16(a1, fA, acc[1][0], 0, 0, 0);
        acc[1][1] = __builtin_amdgcn_mfma_f32_16x16x32_bf16(a1, fB, acc[1][1], 0, 0, 0);
        acc[2][0] = __builtin_amdgcn_mfma_f32_16x16x32_bf16(a2, fA, acc[2][0], 0, 0, 0);
        acc[2][1] = __builtin_amdgcn_mfma_f32_16x16x32_bf16(a2, fB, acc[2][1], 0, 0, 0);
        acc[3][0] = __builtin_amdgcn_mfma_f32_16x16x32_bf16(a3, fA, acc[3][0], 0, 0, 0);
        acc[3][1] = __builtin_amdgcn_mfma_f32_16x16x32_bf16(a3, fB, acc[3][1], 0, 0, 0);
    }
#pragma unroll
    for (int mt = 0; mt < 4; ++mt)
#pragma unroll
        for (int r = 0; r < 4; ++r) {
            int m = mt * 16 + kg * 4 + r;
            if (m < 49) {
                ushort_t* up = u + (size_t)(b * 49 + m) * HW;
                up[pA] = f2bf(acc[mt][0][r]);
                up[pB] = f2bf(acc[mt][1][r]);
            }
        }
}

// ============ K4b: shift-add 49 taps -> sigmoid -> out *= cw*sw ============
__global__ __launch_bounds__(256) void sa_final_kernel(
    float* __restrict__ out, const ushort_t* __restrict__ u,
    const float* __restrict__ cw, const float* __restrict__ sab) {
    __shared__ float cw_l[64];
    int tid = threadIdx.x;
    int b = blockIdx.y;
    int p = blockIdx.x * 256 + tid;
    if (tid < 64) cw_l[tid] = cw[b * 64 + tid];
    __syncthreads();
    int y = p / 192, x = p - y * 192;
    float s = sab[0];
    const ushort_t* ub = u + (size_t)b * 49 * HW;
#pragma unroll
    for (int dy = 0; dy < 7; ++dy)
#pragma unroll
        for (int dx = 0; dx < 7; ++dx) {
            int yy = y + dy - 3, xx = x + dx - 3;
            bool ok = ((unsigned)yy < 192u) && ((unsigned)xx < 192u);
            int ad = ok ? (p + (dy - 3) * 192 + (dx - 3)) : 0;
            float v = bflo((uint_t)ub[(size_t)(dy * 7 + dx) * HW + ad]);
            s += ok ? v : 0.f;
        }
    float swv = 1.f / (1.f + __expf(-s));
#pragma unroll 8
    for (int c = 0; c < 64; ++c) {
        size_t ix = (size_t)(b * 64 + c) * HW + p;
        out[ix] = out[ix] * (cw_l[c] * swv);
    }
}

extern "C" void kernel_launch(void* const* d_in, const int* in_sizes, int n_in,
                              void* d_out, int out_size, void* d_ws, size_t ws_size,
                              hipStream_t stream) {
    const float* x     = (const float*)d_in[0];
    const float* off_w = (const float*)d_in[1];
    const float* off_b = (const float*)d_in[2];
    const float* dw    = (const float*)d_in[3];
    const float* db    = (const float*)d_in[4];
    const float* bn_g  = (const float*)d_in[5];
    const float* bn_b  = (const float*)d_in[6];
    const float* bn_m  = (const float*)d_in[7];
    const float* bn_v  = (const float*)d_in[8];
    const float* ca_w1 = (const float*)d_in[9];
    const float* ca_b1 = (const float*)d_in[10];
    const float* ca_w2 = (const float*)d_in[11];
    const float* ca_b2 = (const float*)d_in[12];
    const float* sa_w  = (const float*)d_in[13];
    const float* sa_b  = (const float*)d_in[14];
    float* out = (float*)d_out;
    float* ws  = (float*)d_ws;

    // ws layout (floats):
    // x_t  [B,HW,64] bf16   @ 0        (9437184 sh = 4718592 fl)
    //   u  [B,49,HW] bf16   @ 0        (aliases x_t; x_t dead after deform)
    // w_bf @4718592  w_off @4737024  scale @4746240  shift @4746304
    // cw @4746368  pooled @4746624
    // partial [64][1152]    @ 4746880  (73728 fl)
    // we_bf [B][64][64] sh  @ 4820608  -> end 4828800 fl = 19.3 MB
    ushort_t* x_t    = (ushort_t*)ws;
    ushort_t* u      = (ushort_t*)ws;
    ushort_t* w_bf   = (ushort_t*)(ws + 4718592);
    ushort_t* w_off  = (ushort_t*)(ws + 4737024);
    float* scale     = ws + 4746240;
    float* shift     = ws + 4746304;
    float* cw        = ws + 4746368;
    float* pooled    = ws + 4746624;
    float* partial   = ws + 4746880;
    ushort_t* we_bf  = (ushort_t*)(ws + 4820608);

    prep_kernel<<<216, 256, 0, stream>>>(dw, db, bn_g, bn_b, bn_m, bn_v, off_w,
                                         w_bf, w_off, scale, shift);
    transpose_kernel<<<576, 256, 0, stream>>>(x, x_t);
    deform_fused_kernel<<<1152, 256, 0, stream>>>(x_t, w_off, off_b, w_bf,
                                                  scale, shift, out, partial);
    reduce_kernel<<<256, 64, 0, stream>>>(partial, pooled);
    ca_kernel<<<1, 256, 0, stream>>>(pooled, ca_w1, ca_b1, ca_w2, ca_b2, sa_w, cw, we_bf);
    tap_gemm_kernel<<<dim3(288, 4), 256, 0, stream>>>(out, we_bf, u);
    sa_final_kernel<<<dim3(144, 4), 256, 0, stream>>>(out, u, cw, sa_b);
}

// Round 7
// 239.173 us; speedup vs baseline: 1.2458x; 1.0726x over previous
//
#include <hip/hip_runtime.h>

#define H_  192
#define W_  192
#define HW  36864
#define B_  4

typedef __attribute__((ext_vector_type(8))) short short8;
typedef __attribute__((ext_vector_type(4))) float f32x4;
typedef __attribute__((ext_vector_type(4))) unsigned int u32x4;
typedef unsigned short ushort_t;
typedef unsigned int uint_t;

__device__ __forceinline__ ushort_t f2bf(float v) {
    uint_t u = __builtin_bit_cast(uint_t, v);
    u += 0x7FFFu + ((u >> 16) & 1u);   // RNE
    return (ushort_t)(u >> 16);
}
__device__ __forceinline__ float bflo(uint_t u) {
    uint_t w = u << 16; return __builtin_bit_cast(float, w);
}
__device__ __forceinline__ float bfhi(uint_t u) {
    uint_t w = u & 0xFFFF0000u; return __builtin_bit_cast(float, w);
}
__device__ __forceinline__ short8 zero8() {
    u32x4 z = {0u, 0u, 0u, 0u};
    return __builtin_bit_cast(short8, z);
}

// ============ K0: weight prep ============
__global__ void prep_kernel(const float* __restrict__ dw, const float* __restrict__ db,
                            const float* __restrict__ g, const float* __restrict__ be,
                            const float* __restrict__ mu, const float* __restrict__ var,
                            const float* __restrict__ ow,
                            ushort_t* __restrict__ w_bf, ushort_t* __restrict__ w_off,
                            float* __restrict__ scale, float* __restrict__ shift) {
    int idx = blockIdx.x * 256 + threadIdx.x;
    if (idx < 36864) {
        int tap = idx >> 12, o = (idx >> 6) & 63, c = idx & 63;
        w_bf[idx] = f2bf(dw[(o * 64 + c) * 9 + tap]);
    }
    int idx2 = idx - 36864;
    if (idx2 >= 0 && idx2 < 18432) {
        int tap = idx2 >> 11, o = (idx2 >> 6) & 31, c = idx2 & 63;
        w_off[idx2] = (o < 18) ? f2bf(ow[(o * 64 + c) * 9 + tap]) : (ushort_t)0;
    }
    if (idx < 64) {
        float s = g[idx] * rsqrtf(var[idx] + 1e-5f);
        scale[idx] = s;
        shift[idx] = (db[idx] - mu[idx]) * s + be[idx];
    }
}

// ============ KT: x [B,C,HW] f32 -> x_t [B,HW,C] bf16 ============
__global__ __launch_bounds__(256) void transpose_kernel(const float* __restrict__ x,
                                                        ushort_t* __restrict__ x_t) {
    __shared__ uint_t tlds[256 * 33];
    int tid = threadIdx.x;
    int b = blockIdx.x / 144;
    int p0 = (blockIdx.x % 144) * 256;
    ushort_t* ts = (ushort_t*)tlds;
    for (int c = 0; c < 64; ++c) {
        float v = x[((size_t)(b * 64 + c)) * HW + p0 + tid];
        ts[tid * 66 + c] = f2bf(v);
    }
    __syncthreads();
#pragma unroll
    for (int j = 0; j < 8; ++j) {
        int chunk = j * 256 + tid;
        int pl = chunk >> 3, s = chunk & 7;
        int bd = pl * 33 + s * 4;
        u32x4 v = {tlds[bd], tlds[bd + 1], tlds[bd + 2], tlds[bd + 3]};
        ((u32x4*)x_t)[(size_t)(b * HW + p0) * 8 + chunk] = v;
    }
}

// ============ helpers for fused deform ============
__device__ __forceinline__ void corner_setup(const float* off_lds, int ploc, int tap,
                                             int ybase, int xbase, int* idx, float* w) {
    float ody = off_lds[ploc * 19 + 2 * tap];
    float odx = off_lds[ploc * 19 + 2 * tap + 1];
    float py = (float)ybase + ody;
    float px = (float)xbase + odx;
    float fy = floorf(py), fx = floorf(px);
    int y0 = (int)fy, x0 = (int)fx;
    float wy = py - fy, wx = px - fx;
    int y0c = min(max(y0, 0), H_ - 1), y1c = min(max(y0 + 1, 0), H_ - 1);
    int x0c = min(max(x0, 0), W_ - 1), x1c = min(max(x0 + 1, 0), W_ - 1);
    float vy0 = (y0 >= 0 && y0 < H_) ? 1.f : 0.f;
    float vy1 = (y0 + 1 >= 0 && y0 + 1 < H_) ? 1.f : 0.f;
    float vx0 = (x0 >= 0 && x0 < W_) ? 1.f : 0.f;
    float vx1 = (x0 + 1 >= 0 && x0 + 1 < W_) ? 1.f : 0.f;
    w[0] = (1.f - wy) * (1.f - wx) * vy0 * vx0;
    w[1] = (1.f - wy) * wx * vy0 * vx1;
    w[2] = wy * (1.f - wx) * vy1 * vx0;
    w[3] = wy * wx * vy1 * vx1;
    idx[0] = (y0c * W_ + x0c) * 64; idx[1] = (y0c * W_ + x1c) * 64;
    idx[2] = (y1c * W_ + x0c) * 64; idx[3] = (y1c * W_ + x1c) * 64;
}

__device__ __forceinline__ short8 interp_frag(const ushort_t* base, const int* idx,
                                              const float* w) {
    u32x4 c0 = *(const u32x4*)(base + idx[0]);
    u32x4 c1 = *(const u32x4*)(base + idx[1]);
    u32x4 c2 = *(const u32x4*)(base + idx[2]);
    u32x4 c3 = *(const u32x4*)(base + idx[3]);
    short8 r;
#pragma unroll
    for (int q = 0; q < 4; ++q) {
        float lo = w[0] * bflo(c0[q]) + w[1] * bflo(c1[q]) + w[2] * bflo(c2[q]) + w[3] * bflo(c3[q]);
        float hi = w[0] * bfhi(c0[q]) + w[1] * bfhi(c1[q]) + w[2] * bfhi(c2[q]) + w[3] * bfhi(c3[q]);
        uint_t p = (uint_t)f2bf(lo) | ((uint_t)f2bf(hi) << 16);
        ((uint_t*)&r)[q] = p;
    }
    return r;
}

// ============ K2: fused offset-conv + deformable conv — 1-wave blocks ============
// Block = 1 wave = 32 positions (2 per thread, pA/pB, full round-4 ILP).
__global__ __launch_bounds__(64, 4) void deform_fused_kernel(
    const ushort_t* __restrict__ x_t, const ushort_t* __restrict__ w_off,
    const float* __restrict__ ob, const ushort_t* __restrict__ w_bf,
    const float* __restrict__ scale_g, const float* __restrict__ shift_g,
    float* __restrict__ out) {
    __shared__ float off_lds[32 * 19];

    int lane = threadIdx.x;
    int tile = (blockIdx.x & 7) * 576 + (blockIdx.x >> 3);   // XCD-bijective (4608 % 8 == 0)
    int b = tile / 1152;
    int p0 = (tile % 1152) * 32;

    int ln = lane & 15, kg = lane >> 4;
    int pA_loc = ln, pB_loc = 16 + ln;
    int pA = p0 + pA_loc, pB = p0 + pB_loc;
    int yA = pA / 192, xA = pA - yA * 192;
    int yB = pB / 192, xB = pB - yB * 192;
    const ushort_t* xt_b = x_t + (size_t)b * (HW * 64);

    // ---- phase 0: offset conv (M=32, rows 0..17 used) ----
    f32x4 ao[2][2];
#pragma unroll
    for (int i = 0; i < 2; ++i)
#pragma unroll
        for (int j = 0; j < 2; ++j) ao[i][j] = (f32x4){0.f, 0.f, 0.f, 0.f};

    for (int tap = 0; tap < 9; ++tap) {
        int ti = tap / 3 - 1, tj = tap % 3 - 1;
        short8 bA[2], bB[2];
        {
            int yy = yA + ti, xx = xA + tj;
            bool v = (yy >= 0 && yy < H_ && xx >= 0 && xx < W_);
            int base = (min(max(yy, 0), H_ - 1) * W_ + min(max(xx, 0), W_ - 1)) * 64;
#pragma unroll
            for (int ks = 0; ks < 2; ++ks) {
                short8 t8 = *(const short8*)(xt_b + base + ks * 32 + kg * 8);
                bA[ks] = v ? t8 : zero8();
            }
        }
        {
            int yy = yB + ti, xx = xB + tj;
            bool v = (yy >= 0 && yy < H_ && xx >= 0 && xx < W_);
            int base = (min(max(yy, 0), H_ - 1) * W_ + min(max(xx, 0), W_ - 1)) * 64;
#pragma unroll
            for (int ks = 0; ks < 2; ++ks) {
                short8 t8 = *(const short8*)(xt_b + base + ks * 32 + kg * 8);
                bB[ks] = v ? t8 : zero8();
            }
        }
        const ushort_t* wt = w_off + tap * 2048;
#pragma unroll
        for (int ks = 0; ks < 2; ++ks) {
            int ch = ks * 32 + kg * 8;
            short8 a0 = *(const short8*)(wt + ln * 64 + ch);
            short8 a1 = *(const short8*)(wt + (16 + ln) * 64 + ch);
            ao[0][0] = __builtin_amdgcn_mfma_f32_16x16x32_bf16(a0, bA[ks], ao[0][0], 0, 0, 0);
            ao[0][1] = __builtin_amdgcn_mfma_f32_16x16x32_bf16(a0, bB[ks], ao[0][1], 0, 0, 0);
            ao[1][0] = __builtin_amdgcn_mfma_f32_16x16x32_bf16(a1, bA[ks], ao[1][0], 0, 0, 0);
            ao[1][1] = __builtin_amdgcn_mfma_f32_16x16x32_bf16(a1, bB[ks], ao[1][1], 0, 0, 0);
        }
    }
#pragma unroll
    for (int mt = 0; mt < 2; ++mt)
#pragma unroll
        for (int r = 0; r < 4; ++r) {
            int m = mt * 16 + kg * 4 + r;
            if (m < 18) {
                float bias = ob[m];
                off_lds[pA_loc * 19 + m] = ao[mt][0][r] + bias;
                off_lds[pB_loc * 19 + m] = ao[mt][1][r] + bias;
            }
        }
    __syncthreads();

    // ---- main: deformable conv (round-4 structure) ----
    f32x4 acc[4][2];
#pragma unroll
    for (int mt = 0; mt < 4; ++mt)
#pragma unroll
        for (int nt = 0; nt < 2; ++nt) acc[mt][nt] = (f32x4){0.f, 0.f, 0.f, 0.f};

    for (int tap = 0; tap < 9; ++tap) {
        int ti = tap / 3 - 1, tj = tap % 3 - 1;
        int iA[4], iB[4];
        float wA[4], wB[4];
        corner_setup(off_lds, pA_loc, tap, yA + ti, xA + tj, iA, wA);
        corner_setup(off_lds, pB_loc, tap, yB + ti, xB + tj, iB, wB);
        const ushort_t* wt = w_bf + tap * 4096;
#pragma unroll
        for (int ks = 0; ks < 2; ++ks) {
            int ch = ks * 32 + kg * 8;
            short8 fA = interp_frag(xt_b + ch, iA, wA);
            short8 fB = interp_frag(xt_b + ch, iB, wB);
            short8 a0 = *(const short8*)(wt + (0 + ln) * 64 + ch);
            short8 a1 = *(const short8*)(wt + (16 + ln) * 64 + ch);
            short8 a2 = *(const short8*)(wt + (32 + ln) * 64 + ch);
            short8 a3 = *(const short8*)(wt + (48 + ln) * 64 + ch);
            acc[0][0] = __builtin_amdgcn_mfma_f32_16x16x32_bf16(a0, fA, acc[0][0], 0, 0, 0);
            acc[0][1] = __builtin_amdgcn_mfma_f32_16x16x32_bf16(a0, fB, acc[0][1], 0, 0, 0);
            acc[1][0] = __builtin_amdgcn_mfma_f32_16x16x32_bf16(a1, fA, acc[1][0], 0, 0, 0);
            acc[1][1] = __builtin_amdgcn_mfma_f32_16x16x32_bf16(a1, fB, acc[1][1], 0, 0, 0);
            acc[2][0] = __builtin_amdgcn_mfma_f32_16x16x32_bf16(a2, fA, acc[2][0], 0, 0, 0);
            acc[2][1] = __builtin_amdgcn_mfma_f32_16x16x32_bf16(a2, fB, acc[2][1], 0, 0, 0);
            acc[3][0] = __builtin_amdgcn_mfma_f32_16x16x32_bf16(a3, fA, acc[3][0], 0, 0, 0);
            acc[3][1] = __builtin_amdgcn_mfma_f32_16x16x32_bf16(a3, fB, acc[3][1], 0, 0, 0);
        }
    }

    // ---- epilogue: BN affine + store (pooled mean moved to pool_kernel) ----
#pragma unroll
    for (int mt = 0; mt < 4; ++mt) {
#pragma unroll
        for (int r = 0; r < 4; ++r) {
            int m = mt * 16 + kg * 4 + r;
            float sc = scale_g[m], sh = shift_g[m];
            size_t orow = (size_t)(b * 64 + m) * HW + p0 + ln;
            out[orow] = acc[mt][0][r] * sc + sh;
            out[orow + 16] = acc[mt][1][r] * sc + sh;
        }
    }
}

// ============ KP: pooled mean over HW (reads out directly) ============
__global__ __launch_bounds__(256) void pool_kernel(const float* __restrict__ h,
                                                   float* __restrict__ pooled) {
    __shared__ float red[4];
    int tid = threadIdx.x;
    const float* src = h + (size_t)blockIdx.x * HW;
    float s = 0.f;
#pragma unroll 4
    for (int i = tid * 4; i < HW; i += 1024) {
        float4 v = *(const float4*)(src + i);
        s += v.x + v.y + v.z + v.w;
    }
#pragma unroll
    for (int d = 1; d < 64; d <<= 1) s += __shfl_xor(s, d, 64);
    if ((tid & 63) == 0) red[tid >> 6] = s;
    __syncthreads();
    if (tid == 0)
        pooled[blockIdx.x] = (red[0] + red[1] + red[2] + red[3]) * (1.0f / (float)HW);
}

// ============ K3: SE MLP -> cw; per-batch bf16 tap-GEMM weights ============
__global__ void ca_kernel(const float* __restrict__ pooled_g,
                          const float* __restrict__ w1, const float* __restrict__ b1,
                          const float* __restrict__ w2, const float* __restrict__ b2,
                          const float* __restrict__ saw, float* __restrict__ cw,
                          ushort_t* __restrict__ we_bf) {
    __shared__ float pooled[256];
    __shared__ float t1[16];
    int t = threadIdx.x;
    int b = t >> 6, o = t & 63;
    pooled[t] = pooled_g[t];
    __syncthreads();
    if (t < 16) {
        int bb = t >> 2, hh = t & 3;
        float a = b1[hh];
        for (int c = 0; c < 64; ++c) a += pooled[bb * 64 + c] * w1[hh * 64 + c];
        t1[t] = fmaxf(a, 0.f);
    }
    __syncthreads();
    float a = b2[o];
#pragma unroll
    for (int h2 = 0; h2 < 4; ++h2) a += t1[b * 4 + h2] * w2[o * 4 + h2];
    float cwv = 1.f / (1.f + __expf(-a));
    cw[t] = cwv;
    for (int tap = 0; tap < 64; ++tap) {
        float v = (tap < 49) ? cwv * saw[o * 49 + tap] : 0.f;
        we_bf[(b * 64 + tap) * 64 + o] = f2bf(v);
    }
}

// ============ K4a: tap GEMM  u[b][t][p] = sum_c we_bf[b][t][c] * h[b][c][p] ============
__global__ __launch_bounds__(256) void tap_gemm_kernel(
    const float* __restrict__ h, const ushort_t* __restrict__ we_bf,
    ushort_t* __restrict__ u) {
    int tid = threadIdx.x;
    int b = blockIdx.y;
    int p0 = blockIdx.x * 128;
    int wid = tid >> 6, lane = tid & 63, ln = lane & 15, kg = lane >> 4;
    int pA = p0 + wid * 32 + ln, pB = pA + 16;
    const float* hb = h + (size_t)b * 64 * HW;
    const ushort_t* wt = we_bf + b * 4096;

    f32x4 acc[4][2];
#pragma unroll
    for (int mt = 0; mt < 4; ++mt)
#pragma unroll
        for (int nt = 0; nt < 2; ++nt) acc[mt][nt] = (f32x4){0.f, 0.f, 0.f, 0.f};

#pragma unroll
    for (int ks = 0; ks < 2; ++ks) {
        int ch = ks * 32 + kg * 8;
        short8 fA, fB;
#pragma unroll
        for (int q = 0; q < 8; ++q) {
            fA[q] = (short)f2bf(hb[(size_t)(ch + q) * HW + pA]);
            fB[q] = (short)f2bf(hb[(size_t)(ch + q) * HW + pB]);
        }
        short8 a0 = *(const short8*)(wt + (0 + ln) * 64 + ch);
        short8 a1 = *(const short8*)(wt + (16 + ln) * 64 + ch);
        short8 a2 = *(const short8*)(wt + (32 + ln) * 64 + ch);
        short8 a3 = *(const short8*)(wt + (48 + ln) * 64 + ch);
        acc[0][0] = __builtin_amdgcn_mfma_f32_16x16x32_bf16(a0, fA, acc[0][0], 0, 0, 0);
        acc[0][1] = __builtin_amdgcn_mfma_f32_16x16x32_bf16(a0, fB, acc[0][1], 0, 0, 0);
        acc[1][0] = __builtin_amdgcn_mfma_f32_16x16x32_bf16(a1, fA, acc[1][0], 0, 0, 0);
        acc[1][1] = __builtin_amdgcn_mfma_f32_16x16x32_bf16(a1, fB, acc[1][1], 0, 0, 0);
        acc[2][0] = __builtin_amdgcn_mfma_f32_16x16x32_bf16(a2, fA, acc[2][0], 0, 0, 0);
        acc[2][1] = __builtin_amdgcn_mfma_f32_16x16x32_bf16(a2, fB, acc[2][1], 0, 0, 0);
        acc[3][0] = __builtin_amdgcn_mfma_f32_16x16x32_bf16(a3, fA, acc[3][0], 0, 0, 0);
        acc[3][1] = __builtin_amdgcn_mfma_f32_16x16x32_bf16(a3, fB, acc[3][1], 0, 0, 0);
    }
#pragma unroll
    for (int mt = 0; mt < 4; ++mt)
#pragma unroll
        for (int r = 0; r < 4; ++r) {
            int m = mt * 16 + kg * 4 + r;
            if (m < 49) {
                ushort_t* up = u + (size_t)(b * 49 + m) * HW;
                up[pA] = f2bf(acc[mt][0][r]);
                up[pB] = f2bf(acc[mt][1][r]);
            }
        }
}

// ============ K4b: shift-add 49 taps -> sigmoid -> out *= cw*sw ============
__global__ __launch_bounds__(256) void sa_final_kernel(
    float* __restrict__ out, const ushort_t* __restrict__ u,
    const float* __restrict__ cw, const float* __restrict__ sab) {
    __shared__ float cw_l[64];
    int tid = threadIdx.x;
    int b = blockIdx.y;
    int p = blockIdx.x * 256 + tid;
    if (tid < 64) cw_l[tid] = cw[b * 64 + tid];
    __syncthreads();
    int y = p / 192, x = p - y * 192;
    float s = sab[0];
    const ushort_t* ub = u + (size_t)b * 49 * HW;
#pragma unroll
    for (int dy = 0; dy < 7; ++dy)
#pragma unroll
        for (int dx = 0; dx < 7; ++dx) {
            int yy = y + dy - 3, xx = x + dx - 3;
            bool ok = ((unsigned)yy < 192u) && ((unsigned)xx < 192u);
            int ad = ok ? (p + (dy - 3) * 192 + (dx - 3)) : 0;
            float v = bflo((uint_t)ub[(size_t)(dy * 7 + dx) * HW + ad]);
            s += ok ? v : 0.f;
        }
    float swv = 1.f / (1.f + __expf(-s));
#pragma unroll 8
    for (int c = 0; c < 64; ++c) {
        size_t ix = (size_t)(b * 64 + c) * HW + p;
        out[ix] = out[ix] * (cw_l[c] * swv);
    }
}

extern "C" void kernel_launch(void* const* d_in, const int* in_sizes, int n_in,
                              void* d_out, int out_size, void* d_ws, size_t ws_size,
                              hipStream_t stream) {
    const float* x     = (const float*)d_in[0];
    const float* off_w = (const float*)d_in[1];
    const float* off_b = (const float*)d_in[2];
    const float* dw    = (const float*)d_in[3];
    const float* db    = (const float*)d_in[4];
    const float* bn_g  = (const float*)d_in[5];
    const float* bn_b  = (const float*)d_in[6];
    const float* bn_m  = (const float*)d_in[7];
    const float* bn_v  = (const float*)d_in[8];
    const float* ca_w1 = (const float*)d_in[9];
    const float* ca_b1 = (const float*)d_in[10];
    const float* ca_w2 = (const float*)d_in[11];
    const float* ca_b2 = (const float*)d_in[12];
    const float* sa_w  = (const float*)d_in[13];
    const float* sa_b  = (const float*)d_in[14];
    float* out = (float*)d_out;
    float* ws  = (float*)d_ws;

    // ws layout (floats):
    // x_t  [B,HW,64] bf16   @ 0        (9437184 sh = 4718592 fl)
    //   u  [B,49,HW] bf16   @ 0        (aliases x_t; x_t dead after deform)
    // w_bf  [9][64][64] sh  @ 4718592  (18432 fl)
    // w_off [9][32][64] sh  @ 4737024  (9216 fl; we_bf aliases it after deform)
    // scale @4746240  shift @4746304  cw @4746368  pooled @4746624
    // end 4746880 fl = 18.99 MB
    ushort_t* x_t    = (ushort_t*)ws;
    ushort_t* u      = (ushort_t*)ws;
    ushort_t* w_bf   = (ushort_t*)(ws + 4718592);
    ushort_t* w_off  = (ushort_t*)(ws + 4737024);
    ushort_t* we_bf  = (ushort_t*)(ws + 4737024);   // aliases w_off (dead after deform)
    float* scale     = ws + 4746240;
    float* shift     = ws + 4746304;
    float* cw        = ws + 4746368;
    float* pooled    = ws + 4746624;

    prep_kernel<<<216, 256, 0, stream>>>(dw, db, bn_g, bn_b, bn_m, bn_v, off_w,
                                         w_bf, w_off, scale, shift);
    transpose_kernel<<<576, 256, 0, stream>>>(x, x_t);
    deform_fused_kernel<<<4608, 64, 0, stream>>>(x_t, w_off, off_b, w_bf,
                                                 scale, shift, out);
    pool_kernel<<<256, 256, 0, stream>>>(out, pooled);
    ca_kernel<<<1, 256, 0, stream>>>(pooled, ca_w1, ca_b1, ca_w2, ca_b2, sa_w, cw, we_bf);
    tap_gemm_kernel<<<dim3(288, 4), 256, 0, stream>>>(out, we_bf, u);
    sa_final_kernel<<<dim3(144, 4), 256, 0, stream>>>(out, u, cw, sa_b);
}

// Round 8
// 224.255 us; speedup vs baseline: 1.3286x; 1.0665x over previous
//
#include <hip/hip_runtime.h>

#define H_  192
#define W_  192
#define HW  36864
#define B_  4

typedef __attribute__((ext_vector_type(8))) short short8;
typedef __attribute__((ext_vector_type(4))) float f32x4;
typedef __attribute__((ext_vector_type(4))) unsigned int u32x4;
typedef unsigned short ushort_t;
typedef unsigned int uint_t;

__device__ __forceinline__ ushort_t f2bf(float v) {
    uint_t u = __builtin_bit_cast(uint_t, v);
    u += 0x7FFFu + ((u >> 16) & 1u);   // RNE
    return (ushort_t)(u >> 16);
}
__device__ __forceinline__ float bflo(uint_t u) {
    uint_t w = u << 16; return __builtin_bit_cast(float, w);
}
__device__ __forceinline__ float bfhi(uint_t u) {
    uint_t w = u & 0xFFFF0000u; return __builtin_bit_cast(float, w);
}
__device__ __forceinline__ short8 zero8() {
    u32x4 z = {0u, 0u, 0u, 0u};
    return __builtin_bit_cast(short8, z);
}

// ============ K0: weight prep ============
__global__ void prep_kernel(const float* __restrict__ dw, const float* __restrict__ db,
                            const float* __restrict__ g, const float* __restrict__ be,
                            const float* __restrict__ mu, const float* __restrict__ var,
                            const float* __restrict__ ow,
                            ushort_t* __restrict__ w_bf, ushort_t* __restrict__ w_off,
                            float* __restrict__ scale, float* __restrict__ shift) {
    int idx = blockIdx.x * 256 + threadIdx.x;
    if (idx < 36864) {
        int tap = idx >> 12, o = (idx >> 6) & 63, c = idx & 63;
        w_bf[idx] = f2bf(dw[(o * 64 + c) * 9 + tap]);
    }
    int idx2 = idx - 36864;
    if (idx2 >= 0 && idx2 < 18432) {
        int tap = idx2 >> 11, o = (idx2 >> 6) & 31, c = idx2 & 63;
        w_off[idx2] = (o < 18) ? f2bf(ow[(o * 64 + c) * 9 + tap]) : (ushort_t)0;
    }
    if (idx < 64) {
        float s = g[idx] * rsqrtf(var[idx] + 1e-5f);
        scale[idx] = s;
        shift[idx] = (db[idx] - mu[idx]) * s + be[idx];
    }
}

// ============ KT: x [B,C,HW] f32 -> x_t [B,HW,C] bf16 ============
__global__ __launch_bounds__(256) void transpose_kernel(const float* __restrict__ x,
                                                        ushort_t* __restrict__ x_t) {
    __shared__ uint_t tlds[256 * 33];
    int tid = threadIdx.x;
    int b = blockIdx.x / 144;
    int p0 = (blockIdx.x % 144) * 256;
    ushort_t* ts = (ushort_t*)tlds;
    for (int c = 0; c < 64; ++c) {
        float v = x[((size_t)(b * 64 + c)) * HW + p0 + tid];
        ts[tid * 66 + c] = f2bf(v);
    }
    __syncthreads();
#pragma unroll
    for (int j = 0; j < 8; ++j) {
        int chunk = j * 256 + tid;
        int pl = chunk >> 3, s = chunk & 7;
        int bd = pl * 33 + s * 4;
        u32x4 v = {tlds[bd], tlds[bd + 1], tlds[bd + 2], tlds[bd + 3]};
        ((u32x4*)x_t)[(size_t)(b * HW + p0) * 8 + chunk] = v;
    }
}

// ============ helpers for fused deform ============
__device__ __forceinline__ void corner_setup(const float* off_lds, int ploc, int tap,
                                             int ybase, int xbase, int* idx, float* w) {
    float ody = off_lds[ploc * 19 + 2 * tap];
    float odx = off_lds[ploc * 19 + 2 * tap + 1];
    float py = (float)ybase + ody;
    float px = (float)xbase + odx;
    float fy = floorf(py), fx = floorf(px);
    int y0 = (int)fy, x0 = (int)fx;
    float wy = py - fy, wx = px - fx;
    int y0c = min(max(y0, 0), H_ - 1), y1c = min(max(y0 + 1, 0), H_ - 1);
    int x0c = min(max(x0, 0), W_ - 1), x1c = min(max(x0 + 1, 0), W_ - 1);
    float vy0 = (y0 >= 0 && y0 < H_) ? 1.f : 0.f;
    float vy1 = (y0 + 1 >= 0 && y0 + 1 < H_) ? 1.f : 0.f;
    float vx0 = (x0 >= 0 && x0 < W_) ? 1.f : 0.f;
    float vx1 = (x0 + 1 >= 0 && x0 + 1 < W_) ? 1.f : 0.f;
    w[0] = (1.f - wy) * (1.f - wx) * vy0 * vx0;
    w[1] = (1.f - wy) * wx * vy0 * vx1;
    w[2] = wy * (1.f - wx) * vy1 * vx0;
    w[3] = wy * wx * vy1 * vx1;
    idx[0] = (y0c * W_ + x0c) * 64; idx[1] = (y0c * W_ + x1c) * 64;
    idx[2] = (y1c * W_ + x0c) * 64; idx[3] = (y1c * W_ + x1c) * 64;
}

__device__ __forceinline__ void load_corners(const ushort_t* base, const int* idx,
                                             u32x4* buf) {
    buf[0] = *(const u32x4*)(base + idx[0]);
    buf[1] = *(const u32x4*)(base + idx[1]);
    buf[2] = *(const u32x4*)(base + idx[2]);
    buf[3] = *(const u32x4*)(base + idx[3]);
}

__device__ __forceinline__ short8 interp_compute(const u32x4* buf, const float* w) {
    short8 r;
#pragma unroll
    for (int q = 0; q < 4; ++q) {
        float lo = w[0] * bflo(buf[0][q]) + w[1] * bflo(buf[1][q]) +
                   w[2] * bflo(buf[2][q]) + w[3] * bflo(buf[3][q]);
        float hi = w[0] * bfhi(buf[0][q]) + w[1] * bfhi(buf[1][q]) +
                   w[2] * bfhi(buf[2][q]) + w[3] * bfhi(buf[3][q]);
        uint_t p = (uint_t)f2bf(lo) | ((uint_t)f2bf(hi) << 16);
        ((uint_t*)&r)[q] = p;
    }
    return r;
}

// ============ K2: fused offset-conv + deformable conv — 1-wave blocks,
// 1-tap-lookahead software pipeline, double-buffered named registers ============
__global__ __launch_bounds__(64, 2) void deform_fused_kernel(
    const ushort_t* __restrict__ x_t, const ushort_t* __restrict__ w_off,
    const float* __restrict__ ob, const ushort_t* __restrict__ w_bf,
    const float* __restrict__ scale_g, const float* __restrict__ shift_g,
    float* __restrict__ out) {
    __shared__ float off_lds[32 * 19];

    int lane = threadIdx.x;
    int tile = (blockIdx.x & 7) * 576 + (blockIdx.x >> 3);   // XCD-bijective
    int b = tile / 1152;
    int p0 = (tile % 1152) * 32;

    int ln = lane & 15, kg = lane >> 4;
    int pA_loc = ln, pB_loc = 16 + ln;
    int pA = p0 + pA_loc, pB = p0 + pB_loc;
    int yA = pA / 192, xA = pA - yA * 192;
    int yB = pB / 192, xB = pB - yB * 192;
    const ushort_t* xt_b = x_t + (size_t)b * (HW * 64);

    // ---- phase 0: offset conv (M=32, rows 0..17 used), 1-tap lookahead ----
    f32x4 ao[2][2];
#pragma unroll
    for (int i = 0; i < 2; ++i)
#pragma unroll
        for (int j = 0; j < 2; ++j) ao[i][j] = (f32x4){0.f, 0.f, 0.f, 0.f};

    short8 pbA[2][2], pbB[2][2];
    bool pvA[2], pvB[2];
    {
        int yy = yA - 1, xx = xA - 1;
        pvA[0] = (yy >= 0 && yy < H_ && xx >= 0 && xx < W_);
        int base = (min(max(yy, 0), H_ - 1) * W_ + min(max(xx, 0), W_ - 1)) * 64;
        pbA[0][0] = *(const short8*)(xt_b + base + kg * 8);
        pbA[0][1] = *(const short8*)(xt_b + base + 32 + kg * 8);
    }
    {
        int yy = yB - 1, xx = xB - 1;
        pvB[0] = (yy >= 0 && yy < H_ && xx >= 0 && xx < W_);
        int base = (min(max(yy, 0), H_ - 1) * W_ + min(max(xx, 0), W_ - 1)) * 64;
        pbB[0][0] = *(const short8*)(xt_b + base + kg * 8);
        pbB[0][1] = *(const short8*)(xt_b + base + 32 + kg * 8);
    }
#pragma unroll
    for (int tap = 0; tap < 9; ++tap) {
        int cur = tap & 1, nxt = cur ^ 1;
        if (tap < 8) {
            int ti = (tap + 1) / 3 - 1, tj = (tap + 1) % 3 - 1;
            {
                int yy = yA + ti, xx = xA + tj;
                pvA[nxt] = (yy >= 0 && yy < H_ && xx >= 0 && xx < W_);
                int base = (min(max(yy, 0), H_ - 1) * W_ + min(max(xx, 0), W_ - 1)) * 64;
                pbA[nxt][0] = *(const short8*)(xt_b + base + kg * 8);
                pbA[nxt][1] = *(const short8*)(xt_b + base + 32 + kg * 8);
            }
            {
                int yy = yB + ti, xx = xB + tj;
                pvB[nxt] = (yy >= 0 && yy < H_ && xx >= 0 && xx < W_);
                int base = (min(max(yy, 0), H_ - 1) * W_ + min(max(xx, 0), W_ - 1)) * 64;
                pbB[nxt][0] = *(const short8*)(xt_b + base + kg * 8);
                pbB[nxt][1] = *(const short8*)(xt_b + base + 32 + kg * 8);
            }
        }
        const ushort_t* wt = w_off + tap * 2048;
#pragma unroll
        for (int ks = 0; ks < 2; ++ks) {
            int ch = ks * 32 + kg * 8;
            short8 a0 = *(const short8*)(wt + ln * 64 + ch);
            short8 a1 = *(const short8*)(wt + (16 + ln) * 64 + ch);
            short8 bA = pvA[cur] ? pbA[cur][ks] : zero8();
            short8 bB = pvB[cur] ? pbB[cur][ks] : zero8();
            ao[0][0] = __builtin_amdgcn_mfma_f32_16x16x32_bf16(a0, bA, ao[0][0], 0, 0, 0);
            ao[0][1] = __builtin_amdgcn_mfma_f32_16x16x32_bf16(a0, bB, ao[0][1], 0, 0, 0);
            ao[1][0] = __builtin_amdgcn_mfma_f32_16x16x32_bf16(a1, bA, ao[1][0], 0, 0, 0);
            ao[1][1] = __builtin_amdgcn_mfma_f32_16x16x32_bf16(a1, bB, ao[1][1], 0, 0, 0);
        }
    }
#pragma unroll
    for (int mt = 0; mt < 2; ++mt)
#pragma unroll
        for (int r = 0; r < 4; ++r) {
            int m = mt * 16 + kg * 4 + r;
            if (m < 18) {
                float bias = ob[m];
                off_lds[pA_loc * 19 + m] = ao[mt][0][r] + bias;
                off_lds[pB_loc * 19 + m] = ao[mt][1][r] + bias;
            }
        }
    __syncthreads();

    // ---- main: deformable conv, 1-tap-lookahead double-buffered gather ----
    f32x4 acc[4][2];
#pragma unroll
    for (int mt = 0; mt < 4; ++mt)
#pragma unroll
        for (int nt = 0; nt < 2; ++nt) acc[mt][nt] = (f32x4){0.f, 0.f, 0.f, 0.f};

    int iA[2][4], iB[2][4];
    float wA[2][4], wB[2][4];
    u32x4 bufA0[2][4], bufA1[2][4], bufB0[2][4], bufB1[2][4];

    corner_setup(off_lds, pA_loc, 0, yA - 1, xA - 1, iA[0], wA[0]);
    corner_setup(off_lds, pB_loc, 0, yB - 1, xB - 1, iB[0], wB[0]);
    load_corners(xt_b + kg * 8,      iA[0], bufA0[0]);
    load_corners(xt_b + 32 + kg * 8, iA[0], bufA1[0]);
    load_corners(xt_b + kg * 8,      iB[0], bufB0[0]);
    load_corners(xt_b + 32 + kg * 8, iB[0], bufB1[0]);

#pragma unroll
    for (int tap = 0; tap < 9; ++tap) {
        int cur = tap & 1, nxt = cur ^ 1;
        if (tap < 8) {
            int ti = (tap + 1) / 3 - 1, tj = (tap + 1) % 3 - 1;
            corner_setup(off_lds, pA_loc, tap + 1, yA + ti, xA + tj, iA[nxt], wA[nxt]);
            corner_setup(off_lds, pB_loc, tap + 1, yB + ti, xB + tj, iB[nxt], wB[nxt]);
            load_corners(xt_b + kg * 8,      iA[nxt], bufA0[nxt]);
            load_corners(xt_b + 32 + kg * 8, iA[nxt], bufA1[nxt]);
            load_corners(xt_b + kg * 8,      iB[nxt], bufB0[nxt]);
            load_corners(xt_b + 32 + kg * 8, iB[nxt], bufB1[nxt]);
        }
        const ushort_t* wt = w_bf + tap * 4096;
        short8 a00 = *(const short8*)(wt + (0 + ln) * 64 + kg * 8);
        short8 a01 = *(const short8*)(wt + (16 + ln) * 64 + kg * 8);
        short8 a02 = *(const short8*)(wt + (32 + ln) * 64 + kg * 8);
        short8 a03 = *(const short8*)(wt + (48 + ln) * 64 + kg * 8);
        short8 a10 = *(const short8*)(wt + (0 + ln) * 64 + 32 + kg * 8);
        short8 a11 = *(const short8*)(wt + (16 + ln) * 64 + 32 + kg * 8);
        short8 a12 = *(const short8*)(wt + (32 + ln) * 64 + 32 + kg * 8);
        short8 a13 = *(const short8*)(wt + (48 + ln) * 64 + 32 + kg * 8);

        short8 fA0 = interp_compute(bufA0[cur], wA[cur]);
        short8 fB0 = interp_compute(bufB0[cur], wB[cur]);
        acc[0][0] = __builtin_amdgcn_mfma_f32_16x16x32_bf16(a00, fA0, acc[0][0], 0, 0, 0);
        acc[0][1] = __builtin_amdgcn_mfma_f32_16x16x32_bf16(a00, fB0, acc[0][1], 0, 0, 0);
        acc[1][0] = __builtin_amdgcn_mfma_f32_16x16x32_bf16(a01, fA0, acc[1][0], 0, 0, 0);
        acc[1][1] = __builtin_amdgcn_mfma_f32_16x16x32_bf16(a01, fB0, acc[1][1], 0, 0, 0);
        acc[2][0] = __builtin_amdgcn_mfma_f32_16x16x32_bf16(a02, fA0, acc[2][0], 0, 0, 0);
        acc[2][1] = __builtin_amdgcn_mfma_f32_16x16x32_bf16(a02, fB0, acc[2][1], 0, 0, 0);
        acc[3][0] = __builtin_amdgcn_mfma_f32_16x16x32_bf16(a03, fA0, acc[3][0], 0, 0, 0);
        acc[3][1] = __builtin_amdgcn_mfma_f32_16x16x32_bf16(a03, fB0, acc[3][1], 0, 0, 0);

        short8 fA1 = interp_compute(bufA1[cur], wA[cur]);
        short8 fB1 = interp_compute(bufB1[cur], wB[cur]);
        acc[0][0] = __builtin_amdgcn_mfma_f32_16x16x32_bf16(a10, fA1, acc[0][0], 0, 0, 0);
        acc[0][1] = __builtin_amdgcn_mfma_f32_16x16x32_bf16(a10, fB1, acc[0][1], 0, 0, 0);
        acc[1][0] = __builtin_amdgcn_mfma_f32_16x16x32_bf16(a11, fA1, acc[1][0], 0, 0, 0);
        acc[1][1] = __builtin_amdgcn_mfma_f32_16x16x32_bf16(a11, fB1, acc[1][1], 0, 0, 0);
        acc[2][0] = __builtin_amdgcn_mfma_f32_16x16x32_bf16(a12, fA1, acc[2][0], 0, 0, 0);
        acc[2][1] = __builtin_amdgcn_mfma_f32_16x16x32_bf16(a12, fB1, acc[2][1], 0, 0, 0);
        acc[3][0] = __builtin_amdgcn_mfma_f32_16x16x32_bf16(a13, fA1, acc[3][0], 0, 0, 0);
        acc[3][1] = __builtin_amdgcn_mfma_f32_16x16x32_bf16(a13, fB1, acc[3][1], 0, 0, 0);
    }

    // ---- epilogue: BN affine + store ----
#pragma unroll
    for (int mt = 0; mt < 4; ++mt) {
#pragma unroll
        for (int r = 0; r < 4; ++r) {
            int m = mt * 16 + kg * 4 + r;
            float sc = scale_g[m], sh = shift_g[m];
            size_t orow = (size_t)(b * 64 + m) * HW + p0 + ln;
            out[orow] = acc[mt][0][r] * sc + sh;
            out[orow + 16] = acc[mt][1][r] * sc + sh;
        }
    }
}

// ============ KP: pooled mean over HW ============
__global__ __launch_bounds__(256) void pool_kernel(const float* __restrict__ h,
                                                   float* __restrict__ pooled) {
    __shared__ float red[4];
    int tid = threadIdx.x;
    const float* src = h + (size_t)blockIdx.x * HW;
    float s = 0.f;
#pragma unroll 4
    for (int i = tid * 4; i < HW; i += 1024) {
        float4 v = *(const float4*)(src + i);
        s += v.x + v.y + v.z + v.w;
    }
#pragma unroll
    for (int d = 1; d < 64; d <<= 1) s += __shfl_xor(s, d, 64);
    if ((tid & 63) == 0) red[tid >> 6] = s;
    __syncthreads();
    if (tid == 0)
        pooled[blockIdx.x] = (red[0] + red[1] + red[2] + red[3]) * (1.0f / (float)HW);
}

// ============ K3: SE MLP -> cw; per-batch bf16 tap-GEMM weights ============
__global__ void ca_kernel(const float* __restrict__ pooled_g,
                          const float* __restrict__ w1, const float* __restrict__ b1,
                          const float* __restrict__ w2, const float* __restrict__ b2,
                          const float* __restrict__ saw, float* __restrict__ cw,
                          ushort_t* __restrict__ we_bf) {
    __shared__ float pooled[256];
    __shared__ float t1[16];
    int t = threadIdx.x;
    int b = t >> 6, o = t & 63;
    pooled[t] = pooled_g[t];
    __syncthreads();
    if (t < 16) {
        int bb = t >> 2, hh = t & 3;
        float a = b1[hh];
        for (int c = 0; c < 64; ++c) a += pooled[bb * 64 + c] * w1[hh * 64 + c];
        t1[t] = fmaxf(a, 0.f);
    }
    __syncthreads();
    float a = b2[o];
#pragma unroll
    for (int h2 = 0; h2 < 4; ++h2) a += t1[b * 4 + h2] * w2[o * 4 + h2];
    float cwv = 1.f / (1.f + __expf(-a));
    cw[t] = cwv;
    for (int tap = 0; tap < 64; ++tap) {
        float v = (tap < 49) ? cwv * saw[o * 49 + tap] : 0.f;
        we_bf[(b * 64 + tap) * 64 + o] = f2bf(v);
    }
}

// ============ K4a: tap GEMM  u[b][t][p] = sum_c we_bf[b][t][c] * h[b][c][p] ============
__global__ __launch_bounds__(256) void tap_gemm_kernel(
    const float* __restrict__ h, const ushort_t* __restrict__ we_bf,
    ushort_t* __restrict__ u) {
    int tid = threadIdx.x;
    int b = blockIdx.y;
    int p0 = blockIdx.x * 128;
    int wid = tid >> 6, lane = tid & 63, ln = lane & 15, kg = lane >> 4;
    int pA = p0 + wid * 32 + ln, pB = pA + 16;
    const float* hb = h + (size_t)b * 64 * HW;
    const ushort_t* wt = we_bf + b * 4096;

    f32x4 acc[4][2];
#pragma unroll
    for (int mt = 0; mt < 4; ++mt)
#pragma unroll
        for (int nt = 0; nt < 2; ++nt) acc[mt][nt] = (f32x4){0.f, 0.f, 0.f, 0.f};

#pragma unroll
    for (int ks = 0; ks < 2; ++ks) {
        int ch = ks * 32 + kg * 8;
        short8 fA, fB;
#pragma unroll
        for (int q = 0; q < 8; ++q) {
            fA[q] = (short)f2bf(hb[(size_t)(ch + q) * HW + pA]);
            fB[q] = (short)f2bf(hb[(size_t)(ch + q) * HW + pB]);
        }
        short8 a0 = *(const short8*)(wt + (0 + ln) * 64 + ch);
        short8 a1 = *(const short8*)(wt + (16 + ln) * 64 + ch);
        short8 a2 = *(const short8*)(wt + (32 + ln) * 64 + ch);
        short8 a3 = *(const short8*)(wt + (48 + ln) * 64 + ch);
        acc[0][0] = __builtin_amdgcn_mfma_f32_16x16x32_bf16(a0, fA, acc[0][0], 0, 0, 0);
        acc[0][1] = __builtin_amdgcn_mfma_f32_16x16x32_bf16(a0, fB, acc[0][1], 0, 0, 0);
        acc[1][0] = __builtin_amdgcn_mfma_f32_16x16x32_bf16(a1, fA, acc[1][0], 0, 0, 0);
        acc[1][1] = __builtin_amdgcn_mfma_f32_16x16x32_bf16(a1, fB, acc[1][1], 0, 0, 0);
        acc[2][0] = __builtin_amdgcn_mfma_f32_16x16x32_bf16(a2, fA, acc[2][0], 0, 0, 0);
        acc[2][1] = __builtin_amdgcn_mfma_f32_16x16x32_bf16(a2, fB, acc[2][1], 0, 0, 0);
        acc[3][0] = __builtin_amdgcn_mfma_f32_16x16x32_bf16(a3, fA, acc[3][0], 0, 0, 0);
        acc[3][1] = __builtin_amdgcn_mfma_f32_16x16x32_bf16(a3, fB, acc[3][1], 0, 0, 0);
    }
#pragma unroll
    for (int mt = 0; mt < 4; ++mt)
#pragma unroll
        for (int r = 0; r < 4; ++r) {
            int m = mt * 16 + kg * 4 + r;
            if (m < 49) {
                ushort_t* up = u + (size_t)(b * 49 + m) * HW;
                up[pA] = f2bf(acc[mt][0][r]);
                up[pB] = f2bf(acc[mt][1][r]);
            }
        }
}

// ============ K4b: shift-add 49 taps -> sigmoid -> out *= cw*sw ============
__global__ __launch_bounds__(256) void sa_final_kernel(
    float* __restrict__ out, const ushort_t* __restrict__ u,
    const float* __restrict__ cw, const float* __restrict__ sab) {
    __shared__ float cw_l[64];
    int tid = threadIdx.x;
    int b = blockIdx.y;
    int p = blockIdx.x * 256 + tid;
    if (tid < 64) cw_l[tid] = cw[b * 64 + tid];
    __syncthreads();
    int y = p / 192, x = p - y * 192;
    float s = sab[0];
    const ushort_t* ub = u + (size_t)b * 49 * HW;
#pragma unroll
    for (int dy = 0; dy < 7; ++dy)
#pragma unroll
        for (int dx = 0; dx < 7; ++dx) {
            int yy = y + dy - 3, xx = x + dx - 3;
            bool ok = ((unsigned)yy < 192u) && ((unsigned)xx < 192u);
            int ad = ok ? (p + (dy - 3) * 192 + (dx - 3)) : 0;
            float v = bflo((uint_t)ub[(size_t)(dy * 7 + dx) * HW + ad]);
            s += ok ? v : 0.f;
        }
    float swv = 1.f / (1.f + __expf(-s));
#pragma unroll 8
    for (int c = 0; c < 64; ++c) {
        size_t ix = (size_t)(b * 64 + c) * HW + p;
        out[ix] = out[ix] * (cw_l[c] * swv);
    }
}

extern "C" void kernel_launch(void* const* d_in, const int* in_sizes, int n_in,
                              void* d_out, int out_size, void* d_ws, size_t ws_size,
                              hipStream_t stream) {
    const float* x     = (const float*)d_in[0];
    const float* off_w = (const float*)d_in[1];
    const float* off_b = (const float*)d_in[2];
    const float* dw    = (const float*)d_in[3];
    const float* db    = (const float*)d_in[4];
    const float* bn_g  = (const float*)d_in[5];
    const float* bn_b  = (const float*)d_in[6];
    const float* bn_m  = (const float*)d_in[7];
    const float* bn_v  = (const float*)d_in[8];
    const float* ca_w1 = (const float*)d_in[9];
    const float* ca_b1 = (const float*)d_in[10];
    const float* ca_w2 = (const float*)d_in[11];
    const float* ca_b2 = (const float*)d_in[12];
    const float* sa_w  = (const float*)d_in[13];
    const float* sa_b  = (const float*)d_in[14];
    float* out = (float*)d_out;
    float* ws  = (float*)d_ws;

    // ws layout (floats) — 18.99 MB total:
    // x_t [B,HW,64] bf16 @0 (4718592 fl); u aliases x_t after deform
    // w_bf @4718592 (18432 fl); w_off @4737024 (9216 fl; we_bf aliases after deform)
    // scale @4746240  shift @4746304  cw @4746368  pooled @4746624
    ushort_t* x_t    = (ushort_t*)ws;
    ushort_t* u      = (ushort_t*)ws;
    ushort_t* w_bf   = (ushort_t*)(ws + 4718592);
    ushort_t* w_off  = (ushort_t*)(ws + 4737024);
    ushort_t* we_bf  = (ushort_t*)(ws + 4737024);
    float* scale     = ws + 4746240;
    float* shift     = ws + 4746304;
    float* cw        = ws + 4746368;
    float* pooled    = ws + 4746624;

    prep_kernel<<<216, 256, 0, stream>>>(dw, db, bn_g, bn_b, bn_m, bn_v, off_w,
                                         w_bf, w_off, scale, shift);
    transpose_kernel<<<576, 256, 0, stream>>>(x, x_t);
    deform_fused_kernel<<<4608, 64, 0, stream>>>(x_t, w_off, off_b, w_bf,
                                                 scale, shift, out);
    pool_kernel<<<256, 256, 0, stream>>>(out, pooled);
    ca_kernel<<<1, 256, 0, stream>>>(pooled, ca_w1, ca_b1, ca_w2, ca_b2, sa_w, cw, we_bf);
    tap_gemm_kernel<<<dim3(288, 4), 256, 0, stream>>>(out, we_bf, u);
    sa_final_kernel<<<dim3(144, 4), 256, 0, stream>>>(out, u, cw, sa_b);
}